// Round 3
// baseline (358.759 us; speedup 1.0000x reference)
//
#include <hip/hip_runtime.h>
#include <hip/hip_bf16.h>

#define IN_DIM  64
#define HID     128
#define OUT_DIM 32

typedef short v8s __attribute__((ext_vector_type(8)));
typedef float v4f __attribute__((ext_vector_type(4)));

__device__ __forceinline__ short f2bf(float f) {
    unsigned u = __builtin_bit_cast(unsigned, f);
    unsigned r = u + 0x7FFFu + ((u >> 16) & 1u);
    return (short)(r >> 16);
}
__device__ __forceinline__ float swishf(float v) {
    return __fdividef(v, 1.0f + __expf(-v));
}
__device__ __forceinline__ uint2 swish_pack(v4f a) {
    float s0 = swishf(a[0]), s1 = swishf(a[1]), s2 = swishf(a[2]), s3 = swishf(a[3]);
    __hip_bfloat162 p0 = __float22bfloat162_rn(make_float2(s0, s1));
    __hip_bfloat162 p1 = __float22bfloat162_rn(make_float2(s2, s3));
    uint2 r; r.x = *(unsigned*)&p0; r.y = *(unsigned*)&p1; return r;
}

// pre-convert x to bf16 once per launch (reused by all 32 subnets)
__global__ void cvt_x(const float* __restrict__ x, uint2* __restrict__ xb, int n4) {
    int i = blockIdx.x * 256 + threadIdx.x;
    if (i < n4) {
        float4 f = ((const float4*)x)[i];
        __hip_bfloat162 p0 = __float22bfloat162_rn(make_float2(f.x, f.y));
        __hip_bfloat162 p1 = __float22bfloat162_rn(make_float2(f.z, f.w));
        uint2 r; r.x = *(unsigned*)&p0; r.y = *(unsigned*)&p1;
        xb[i] = r;
    }
}

// Channel-split: wave w owns output channels [16w,16w+16); its weight A-frags
// live in REGISTERS (loaded once). Only H transits LDS, fragment-major +
// XOR-swizzled, double-buffered. Tile = 128 rows; 3 barriers/tile.
// LDS = 2*32KB (H) + 4KB (head reduce) -> 2 blocks/CU -> 4 waves/SIMD.
__global__ __launch_bounds__(512, 4)
void subnet_mlp(const float* __restrict__ x, const ushort* __restrict__ xbf,
                const float* __restrict__ W1, const float* __restrict__ b1,
                const float* __restrict__ Wh, const float* __restrict__ bh,
                const float* __restrict__ Wo, const float* __restrict__ bo,
                float* __restrict__ out, int n_iters)
{
    __shared__ __align__(16) unsigned char sH[2][128 * 256];  // [row 0..127][8B slot 0..31]
    __shared__ __align__(16) float sRed[128][8];

    const int tid   = threadIdx.x;
    const int o     = blockIdx.x >> 4;
    const int slice = blockIdx.x & 15;
    const int lane  = tid & 63;
    const int w     = tid >> 6;     // wave -> channel group [16w, 16w+16)
    const int n     = lane & 15;    // row-in-ntile / A m-index
    const int q     = lane >> 4;    // quad -> k chunk q*8, C rows 4q..4q+3

    // ---- one-time: weight fragments into registers ----
    const int c = 16 * w + n;       // A-operand channel (m = n)
    v8s a1[2], ah[2][4];
    {
        const float* wp = W1 + (size_t)o * IN_DIM * HID + c;
        #pragma unroll
        for (int kc = 0; kc < 2; ++kc) {
            v8s v;
            #pragma unroll
            for (int j = 0; j < 8; ++j) v[j] = f2bf(wp[(kc * 32 + q * 8 + j) * HID]);
            a1[kc] = v;
        }
    }
    #pragma unroll
    for (int l = 0; l < 2; ++l) {
        const float* wp = Wh + (size_t)(l * OUT_DIM + o) * HID * HID + c;
        #pragma unroll
        for (int kc = 0; kc < 4; ++kc) {
            v8s v;
            #pragma unroll
            for (int j = 0; j < 8; ++j) v[j] = f2bf(wp[(kc * 32 + q * 8 + j) * HID]);
            ah[l][kc] = v;
        }
    }
    const int ch4 = 16 * w + 4 * q;              // this lane's 4 C-channels
    const v4f b1v = *(const v4f*)&b1[o * HID + ch4];
    const v4f bh0 = *(const v4f*)&bh[o * HID + ch4];
    const v4f bh1 = *(const v4f*)&bh[(OUT_DIM + o) * HID + ch4];
    const v4f wov = *(const v4f*)&Wo[o * HID + ch4];
    const float bov = bo[o];

    // LDS addressing: row block = 256B of 32 uint2 slots; slot = (w_src^(n&7))*4 + q_w
    const int wr_off = (n << 8) + ((((w ^ (n & 7)) << 2) | q) << 3);
    int rd_off[4];
    #pragma unroll
    for (int kc = 0; kc < 4; ++kc)
        rd_off[kc] = (n << 8) + (((((2 * kc + (q >> 1)) ^ (n & 7)) << 2) | (2 * (q & 1))) << 3);

    for (int it = 0; it < n_iters; ++it) {
        const int base = (slice * n_iters + it) * 128;
        v4f acc[8];

        // ================= layer 1 (x from global bf16) =================
        #pragma unroll
        for (int t = 0; t < 8; ++t) acc[t] = b1v;
        #pragma unroll
        for (int t = 0; t < 8; ++t) {
            #pragma unroll
            for (int kc = 0; kc < 2; ++kc) {
                v8s xv;
                if (xbf) {
                    xv = *(const v8s*)&xbf[(size_t)(base + t * 16 + n) * IN_DIM + kc * 32 + q * 8];
                } else {
                    const float* xp = x + (size_t)(base + t * 16 + n) * IN_DIM + kc * 32 + q * 8;
                    float4 f0 = ((const float4*)xp)[0];
                    float4 f1 = ((const float4*)xp)[1];
                    union { v8s v; unsigned u[4]; } cv;
                    __hip_bfloat162 p;
                    p = __float22bfloat162_rn(make_float2(f0.x, f0.y)); cv.u[0] = *(unsigned*)&p;
                    p = __float22bfloat162_rn(make_float2(f0.z, f0.w)); cv.u[1] = *(unsigned*)&p;
                    p = __float22bfloat162_rn(make_float2(f1.x, f1.y)); cv.u[2] = *(unsigned*)&p;
                    p = __float22bfloat162_rn(make_float2(f1.z, f1.w)); cv.u[3] = *(unsigned*)&p;
                    xv = cv.v;
                }
                acc[t] = __builtin_amdgcn_mfma_f32_16x16x32_bf16(a1[kc], xv, acc[t], 0, 0, 0);
            }
        }
        #pragma unroll
        for (int t = 0; t < 8; ++t)
            *(uint2*)&sH[0][t * 4096 + wr_off] = swish_pack(acc[t]);
        __syncthreads();

        // ================= hidden layer 2 =================
        #pragma unroll
        for (int t = 0; t < 8; ++t) {
            v4f a = bh0;
            #pragma unroll
            for (int kc = 0; kc < 4; ++kc) {
                v8s hb = *(const v8s*)&sH[0][t * 4096 + rd_off[kc]];
                a = __builtin_amdgcn_mfma_f32_16x16x32_bf16(ah[0][kc], hb, a, 0, 0, 0);
            }
            acc[t] = a;
        }
        #pragma unroll
        for (int t = 0; t < 8; ++t)
            *(uint2*)&sH[1][t * 4096 + wr_off] = swish_pack(acc[t]);
        __syncthreads();

        // ================= hidden layer 3 + fused head =================
        #pragma unroll
        for (int t = 0; t < 8; ++t) {
            v4f a = bh1;
            #pragma unroll
            for (int kc = 0; kc < 4; ++kc) {
                v8s hb = *(const v8s*)&sH[1][t * 4096 + rd_off[kc]];
                a = __builtin_amdgcn_mfma_f32_16x16x32_bf16(ah[1][kc], hb, a, 0, 0, 0);
            }
            float p = swishf(a[0]) * wov[0] + swishf(a[1]) * wov[1]
                    + swishf(a[2]) * wov[2] + swishf(a[3]) * wov[3];
            p += __shfl_xor(p, 16);
            p += __shfl_xor(p, 32);
            if (q == 0) sRed[t * 16 + n][w] = p;
        }
        __syncthreads();

        // cross-wave head reduce + store (waves 0-1); safe without extra barrier:
        // next sRed write is after the next tile's 2nd barrier.
        if (tid < 128) {
            v4f r0 = *(const v4f*)&sRed[tid][0];
            v4f r1 = *(const v4f*)&sRed[tid][4];
            float s = r0[0] + r0[1] + r0[2] + r0[3] + r1[0] + r1[1] + r1[2] + r1[3];
            out[(size_t)(base + tid) * OUT_DIM + o] = s + bov;
        }
    }
}

extern "C" void kernel_launch(void* const* d_in, const int* in_sizes, int n_in,
                              void* d_out, int out_size, void* d_ws, size_t ws_size,
                              hipStream_t stream) {
    const float* x  = (const float*)d_in[0];
    const float* W1 = (const float*)d_in[1];
    const float* b1 = (const float*)d_in[2];
    const float* Wh = (const float*)d_in[3];
    const float* bh = (const float*)d_in[4];
    const float* Wo = (const float*)d_in[5];
    const float* bo = (const float*)d_in[6];
    float* out = (float*)d_out;

    const int N       = in_sizes[0] / IN_DIM;   // 32768
    const int n_iters = N / (16 * 128);         // 16 tiles per block

    const size_t xb_bytes = (size_t)N * IN_DIM * 2;
    const ushort* xbf = nullptr;
    if (ws_size >= xb_bytes) {
        int n4 = N * IN_DIM / 4;
        cvt_x<<<(n4 + 255) / 256, 256, 0, stream>>>(x, (uint2*)d_ws, n4);
        xbf = (const ushort*)d_ws;
    }

    dim3 grid(OUT_DIM * 16);    // 512 blocks: 32 subnets x 16 slices, 2/CU
    dim3 block(512);
    subnet_mlp<<<grid, block, 0, stream>>>(x, xbf, W1, b1, Wh, bh, Wo, bo, out, n_iters);
}